// Round 5
// baseline (244.568 us; speedup 1.0000x reference)
//
#include <hip/hip_runtime.h>
#include <hip/hip_bf16.h>

// DecLayer: h_V(4,2048,128) h_E(4,2048,48,384) f32 -> out(4,2048,128) f32
// ws layout (bytes): [0, 425984) bf16 weights (w1f,w2f,w3f fragment-order; wf1t,wf2t row-order)
//                    [425984, 4620288) V1 f32 [8192][128]
//                    [4620288, 8814592) h (post-LN1) f32 [8192][128]

typedef __bf16 bf16x8 __attribute__((ext_vector_type(8)));
typedef __bf16 bf16x4 __attribute__((ext_vector_type(4)));
typedef float f32x4 __attribute__((ext_vector_type(4)));

#define HH 128
#define EE 384
#define KK 48

__device__ __forceinline__ float gelu_f(float x) {
  // tanh-approx gelu = x * sigmoid(2*(0.79788456 x + 0.03567741 x^3))
  float x2 = x * x;
  float u = x * (-1.5957691216f - 0.0713548163f * x2);
  float e = __expf(u);
  return __fdividef(x, 1.0f + e);
}

__device__ __forceinline__ bf16x8 cvt8v(f32x4 a, f32x4 b) {
  bf16x8 r;
  #pragma unroll
  for (int i = 0; i < 4; ++i) { r[i] = (__bf16)a[i]; r[i + 4] = (__bf16)b[i]; }
  return r;
}

__device__ __forceinline__ f32x4 mfma16(bf16x8 a, bf16x8 b, f32x4 c) {
  return __builtin_amdgcn_mfma_f32_16x16x32_bf16(a, b, c, 0, 0, 0);
}

__device__ __forceinline__ void gload16(const void* g, void* l) {
  __builtin_amdgcn_global_load_lds(
      (const __attribute__((address_space(1))) void*)g,
      (__attribute__((address_space(3))) void*)l, 16, 0, 0);
}

// ---------------- weight prep ----------------
// w1f/w2f/w3f in MFMA-fragment order: elem(kc,n,lane,t) = W^T[n*16+(lane&15)][kc*32+(lane>>4)*8+t]
// so a wave's B-load for (kc,n) is ONE contiguous 1KB fetch at ((kc*8+n)*64+lane)*8.
__global__ void prep_kernel(const float* __restrict__ w1, const float* __restrict__ w2,
                            const float* __restrict__ w3, const float* __restrict__ wf1,
                            const float* __restrict__ wf2, __bf16* __restrict__ out) {
  int idx = blockIdx.x * 256 + threadIdx.x;
  if (idx < 49152) {                       // w1f (edge part of w1: rows 128..511)
    int t = idx & 7, lane = (idx >> 3) & 63, n = (idx >> 9) & 7, kc = idx >> 12;
    int e = kc * 32 + (lane >> 4) * 8 + t, h = n * 16 + (lane & 15);
    out[idx] = (__bf16)w1[(128 + e) * 128 + h];
  } else if (idx < 65536) {                // w2f
    int u = idx - 49152;
    int t = u & 7, lane = (u >> 3) & 63, n = (u >> 9) & 7, kc = u >> 12;
    int e = kc * 32 + (lane >> 4) * 8 + t, h = n * 16 + (lane & 15);
    out[idx] = (__bf16)w2[e * 128 + h];
  } else if (idx < 81920) {                // w3f
    int u = idx - 65536;
    int t = u & 7, lane = (u >> 3) & 63, n = (u >> 9) & 7, kc = u >> 12;
    int e = kc * 32 + (lane >> 4) * 8 + t, h = n * 16 + (lane & 15);
    out[idx] = (__bf16)w3[e * 128 + h];
  } else if (idx < 147456) {               // wf1t[512][128]: wf1t[f][h] = wf1[h][f]
    int t = idx - 81920; int f = t >> 7, h = t & 127;
    out[idx] = (__bf16)wf1[h * 512 + f];
  } else if (idx < 212992) {               // wf2t[128][512]: wf2t[h][f] = wf2[f][h]
    int t = idx - 147456; int h = t >> 9, f = t & 511;
    out[idx] = (__bf16)wf2[f * 128 + h];
  }
}

// ---------------- V1[p][h] = b1[h] + sum_i h_V[p][i] * w1[i][h]  (i<128) ----------------
__global__ __launch_bounds__(128) void v1_kernel(const float* __restrict__ hV,
                                                 const float* __restrict__ w1,
                                                 const float* __restrict__ b1,
                                                 float* __restrict__ V1) {
  __shared__ __align__(16) float sV[16][128];
  const int tid = threadIdx.x;
  const long p0 = (long)blockIdx.x * 16;
  for (int i = 0; i < 16; ++i) sV[i][tid] = hV[(p0 + i) * HH + tid];
  __syncthreads();
  float acc[16];
  float bb = b1[tid];
  #pragma unroll
  for (int p = 0; p < 16; ++p) acc[p] = bb;
  for (int k = 0; k < 128; k += 4) {
    float wa = w1[(k + 0) * HH + tid];
    float wb = w1[(k + 1) * HH + tid];
    float wc = w1[(k + 2) * HH + tid];
    float wd = w1[(k + 3) * HH + tid];
    #pragma unroll
    for (int p = 0; p < 16; ++p) {
      float4 h4 = *(const float4*)&sV[p][k];
      acc[p] = fmaf(h4.x, wa, fmaf(h4.y, wb, fmaf(h4.z, wc, fmaf(h4.w, wd, acc[p]))));
    }
  }
  #pragma unroll
  for (int p = 0; p < 16; ++p) V1[(p0 + p) * HH + tid] = acc[p];
}

// ---------------- fused message kernel ----------------
// 4 waves/block, wave w owns position blockIdx.x*4+w end-to-end. No barriers.
// GEMM1 A staged via depth-3 rotating wave-private LDS buffers (counted vmcnt waits).
// After GEMM1, staging bufs 0-1 (12KB) are reused as the h1/h2 buffer (48 x 256B rows).
// Swapped MFMA: lane (fr,fg) holds acc[m][n][j] = h_msg[msg=m*16+fr][h=n*16+fg*4+j].
__global__ __launch_bounds__(256, 2) void msg_kernel(
    const float* __restrict__ hE, const float* __restrict__ hV,
    const float* __restrict__ maskE,
    const __bf16* __restrict__ w1f, const __bf16* __restrict__ w2f,
    const __bf16* __restrict__ w3f, const float* __restrict__ V1,
    const float* __restrict__ b2, const float* __restrict__ b3,
    const float* __restrict__ g1, const float* __restrict__ bn1,
    float* __restrict__ outH) {
  __shared__ __align__(16) float sStage[4][4608];   // 18KB/wave: 3 x 6KB A-bufs; bufs0-1 reused as h

  const int tid = threadIdx.x;
  const int lane = tid & 63;
  const int w = tid >> 6;
  const long p = (long)blockIdx.x * 4 + w;
  const int fr = lane & 15;
  const int fg = lane >> 4;
  char* stDst = (char*)&sStage[w][0];
  const int swz = (fr & 7) << 4;

  const int r_l = lane >> 3;                        // 0..7
  const int cswz = ((lane & 7) ^ r_l) * 16;         // pre-swizzled source col-bytes
  const char* gA = (const char*)(hE + p * KK * (long)EE) + r_l * (EE * 4) + cswz;

  const __bf16* b1p = w1f + lane * 8;
  const __bf16* b2p = w2f + lane * 8;
  const __bf16* b3p = w3f + lane * 8;

  f32x4 acc[3][8];
  #pragma unroll
  for (int m = 0; m < 3; ++m)
    #pragma unroll
    for (int n = 0; n < 8; ++n) acc[m][n] = (f32x4){0.f, 0.f, 0.f, 0.f};

  bf16x8 BA[8], BB[8], BC[8];

#define STAGEA(KC, BUFI) { \
    _Pragma("unroll") for (int q_ = 0; q_ < 6; ++q_) \
      gload16(gA + (KC) * 128 + q_ * (8 * EE * 4), stDst + (BUFI) * 6144 + q_ * 1024); }
#define LOADB(BUF, BP, KC) { \
    _Pragma("unroll") for (int n_ = 0; n_ < 8; ++n_) \
      BUF[n_] = *(const bf16x8*)((BP) + ((KC) * 8 + n_) * 512); }
#define WAITV(N) asm volatile("s_waitcnt vmcnt(" #N ")" ::: "memory")
#define WAITL   asm volatile("s_waitcnt lgkmcnt(0)" ::: "memory")
#define SBAR    __builtin_amdgcn_sched_barrier(0)

// one GEMM1 iteration: wait(A(kc),B(kc) landed) -> read A -> issue B(kc+2) -> issue A(kc+3) -> MFMA
#define GITER(WAITN, BUFI, BUSE, BLD, BLP, BLKC, DOSTAGE, STKC, STBUF) { \
    WAITV(WAITN); \
    const char* rb_ = stDst + (BUFI) * 6144; \
    f32x4 x0_ = *(const f32x4*)(rb_ + fr * 128 + ((fg * 32) ^ swz)); \
    f32x4 x1_ = *(const f32x4*)(rb_ + fr * 128 + ((fg * 32 + 16) ^ swz)); \
    f32x4 x2_ = *(const f32x4*)(rb_ + (16 + fr) * 128 + ((fg * 32) ^ swz)); \
    f32x4 x3_ = *(const f32x4*)(rb_ + (16 + fr) * 128 + ((fg * 32 + 16) ^ swz)); \
    f32x4 x4_ = *(const f32x4*)(rb_ + (32 + fr) * 128 + ((fg * 32) ^ swz)); \
    f32x4 x5_ = *(const f32x4*)(rb_ + (32 + fr) * 128 + ((fg * 32 + 16) ^ swz)); \
    WAITL; SBAR; \
    LOADB(BLD, BLP, BLKC); \
    SBAR; \
    if (DOSTAGE) STAGEA(STKC, STBUF); \
    SBAR; \
    bf16x8 af0 = cvt8v(x0_, x1_); \
    bf16x8 af1 = cvt8v(x2_, x3_); \
    bf16x8 af2 = cvt8v(x4_, x5_); \
    _Pragma("unroll") for (int n_ = 0; n_ < 8; ++n_) { \
      acc[0][n_] = mfma16(BUSE[n_], af0, acc[0][n_]); \
      acc[1][n_] = mfma16(BUSE[n_], af1, acc[1][n_]); \
      acc[2][n_] = mfma16(BUSE[n_], af2, acc[2][n_]); } }

#define STEPL(BUSE, KC) { \
    const int cb_ = (((KC) * 64 + fg * 16) ^ swz); \
    bf16x8 af0 = *(const bf16x8*)(stDst + fr * 256 + cb_); \
    bf16x8 af1 = *(const bf16x8*)(stDst + (16 + fr) * 256 + cb_); \
    bf16x8 af2 = *(const bf16x8*)(stDst + (32 + fr) * 256 + cb_); \
    _Pragma("unroll") for (int n_ = 0; n_ < 8; ++n_) { \
      acc[0][n_] = mfma16(BUSE[n_], af0, acc[0][n_]); \
      acc[1][n_] = mfma16(BUSE[n_], af1, acc[1][n_]); \
      acc[2][n_] = mfma16(BUSE[n_], af2, acc[2][n_]); } }
#define EPI(BIASQ) { \
    _Pragma("unroll") for (int m_ = 0; m_ < 3; ++m_) { \
      const int rb_ = (m_ * 16 + fr) * 256; \
      _Pragma("unroll") for (int n_ = 0; n_ < 8; ++n_) { \
        bf16x4 t_; \
        _Pragma("unroll") for (int j_ = 0; j_ < 4; ++j_) \
          t_[j_] = (__bf16)gelu_f(acc[m_][n_][j_] + BIASQ[n_][j_]); \
        *(bf16x4*)(stDst + rb_ + ((n_ * 32 + fg * 8) ^ swz)) = t_; \
        acc[m_][n_] = (f32x4){0.f, 0.f, 0.f, 0.f}; } } }

  // ---- prologue: queue = [A0 B0 A1 B1 A2] = 34 outstanding ----
  STAGEA(0, 0); SBAR;
  LOADB(BA, b1p, 0); SBAR;
  STAGEA(1, 1); SBAR;
  LOADB(BB, b1p, 1); SBAR;
  STAGEA(2, 2); SBAR;

  // ---- GEMM1: 12 iterations, steady wait vmcnt(20) ----
  GITER(20, 0, BA, BC, b1p, 2, 1, 3, 0);
  GITER(20, 1, BB, BA, b1p, 3, 1, 4, 1);
  GITER(20, 2, BC, BB, b1p, 4, 1, 5, 2);
  GITER(20, 0, BA, BC, b1p, 5, 1, 6, 0);
  GITER(20, 1, BB, BA, b1p, 6, 1, 7, 1);
  GITER(20, 2, BC, BB, b1p, 7, 1, 8, 2);
  GITER(20, 0, BA, BC, b1p, 8, 1, 9, 0);
  GITER(20, 1, BB, BA, b1p, 9, 1, 10, 1);
  GITER(20, 2, BC, BB, b1p, 10, 1, 11, 2);
  GITER(20, 0, BA, BC, b1p, 11, 0, 0, 0);
  GITER(14, 1, BB, BA, b2p, 0, 0, 0, 0);   // prefetch GEMM2 B0
  GITER(8,  2, BC, BB, b2p, 1, 0, 0, 0);   // prefetch GEMM2 B1

  // epilogue 1: + V1 (has b1), gelu -> h1 in reused staging LDS (wave-local)
  {
    f32x4 vq[8];
    #pragma unroll
    for (int n = 0; n < 8; ++n) vq[n] = *(const f32x4*)(V1 + p * HH + n * 16 + fg * 4);
    EPI(vq);
  }

  // ---- GEMM2: h1(48x128) @ w2 ----
  STEPL(BA, 0); LOADB(BC, b2p, 2);
  STEPL(BB, 1); LOADB(BA, b2p, 3);
  STEPL(BC, 2); LOADB(BB, b3p, 0);
  STEPL(BA, 3); LOADB(BC, b3p, 1);
  {
    f32x4 bq[8];
    #pragma unroll
    for (int n = 0; n < 8; ++n) bq[n] = *(const f32x4*)(b2 + n * 16 + fg * 4);
    EPI(bq);
  }

  // ---- GEMM3: h2(48x128) @ w3 ----
  STEPL(BB, 0); LOADB(BA, b3p, 2);
  STEPL(BC, 1); LOADB(BB, b3p, 3);
  STEPL(BA, 2);
  STEPL(BB, 3);

  // ---- masked K-reduction, fully in-register ----
  const float mk0 = maskE[p * KK + fr];
  const float mk1 = maskE[p * KK + 16 + fr];
  const float mk2 = maskE[p * KK + 32 + fr];
  f32x4 red[8];
  {
    #pragma unroll
    for (int n = 0; n < 8; ++n) {
      f32x4 bq = *(const f32x4*)(b3 + n * 16 + fg * 4);
      red[n] = mk0 * (acc[0][n] + bq) + mk1 * (acc[1][n] + bq) + mk2 * (acc[2][n] + bq);
    }
    #pragma unroll
    for (int off = 1; off <= 8; off <<= 1)
      #pragma unroll
      for (int n = 0; n < 8; ++n)
        #pragma unroll
        for (int j = 0; j < 4; ++j)
          red[n][j] += __shfl_xor(red[n][j], off);
  }

  // ---- LN1: x = hV + dh/30, normalize over 128 ----
  {
    f32x4 xq[8];
    #pragma unroll
    for (int n = 0; n < 8; ++n)
      xq[n] = *(const f32x4*)(hV + p * HH + n * 16 + fg * 4) + red[n] * (1.f / 30.f);
    float s = 0.f;
    #pragma unroll
    for (int n = 0; n < 8; ++n)
      #pragma unroll
      for (int j = 0; j < 4; ++j) s += xq[n][j];
    s += __shfl_xor(s, 16); s += __shfl_xor(s, 32);
    float mean = s * (1.f / 128.f);
    float qv = 0.f;
    #pragma unroll
    for (int n = 0; n < 8; ++n)
      #pragma unroll
      for (int j = 0; j < 4; ++j) { float e = xq[n][j] - mean; qv += e * e; }
    qv += __shfl_xor(qv, 16); qv += __shfl_xor(qv, 32);
    float rs = rsqrtf(qv * (1.f / 128.f) + 1e-5f);
    if (fr == 0) {
      #pragma unroll
      for (int n = 0; n < 8; ++n) {
        f32x4 gq = *(const f32x4*)(g1 + n * 16 + fg * 4);
        f32x4 bq = *(const f32x4*)(bn1 + n * 16 + fg * 4);
        f32x4 o;
        #pragma unroll
        for (int j = 0; j < 4; ++j) o[j] = (xq[n][j] - mean) * rs * gq[j] + bq[j];
        *(f32x4*)(outH + p * HH + n * 16 + fg * 4) = o;
      }
    }
  }
#undef STAGEA
#undef LOADB
#undef WAITV
#undef WAITL
#undef SBAR
#undef GITER
#undef STEPL
#undef EPI
}

// ---------------- FFN + LN2 + mask ----------------
__global__ __launch_bounds__(256, 2) void ffn_kernel(
    const float* __restrict__ xin, const __bf16* __restrict__ wf1t,
    const float* __restrict__ bf1, const __bf16* __restrict__ wf2t,
    const float* __restrict__ bf2, const float* __restrict__ g2,
    const float* __restrict__ bn2, const float* __restrict__ maskV,
    float* __restrict__ out) {
  __shared__ __align__(16) __bf16 sX[32][136];
  __shared__ __align__(16) __bf16 sH1[32][520];
  __shared__ __align__(16) float sOut[32][132];
  const int tid = threadIdx.x, lane = tid & 63, w = tid >> 6;
  const long row0 = (long)blockIdx.x * 32;
  const int fr = lane & 15, fg = lane >> 4;

  {  // stage X -> bf16
    int r = tid >> 3, c = (tid & 7) * 16;
    const float* src = xin + (row0 + r) * HH + c;
    f32x4 v0 = *(const f32x4*)src, v1 = *(const f32x4*)(src + 4);
    f32x4 v2 = *(const f32x4*)(src + 8), v3 = *(const f32x4*)(src + 12);
    *(bf16x8*)&sX[r][c] = cvt8v(v0, v1);
    *(bf16x8*)&sX[r][c + 8] = cvt8v(v2, v3);
  }
  __syncthreads();

  // GEMM1: x(32x128) @ wf1(128x512); wave w owns cols [w*128, w*128+128)
  f32x4 a1[2][8];
  #pragma unroll
  for (int m = 0; m < 2; ++m)
    #pragma unroll
    for (int n = 0; n < 8; ++n) a1[m][n] = (f32x4){0.f, 0.f, 0.f, 0.f};
  for (int kc = 0; kc < 4; ++kc) {
    int k0 = kc * 32;
    bf16x8 af0 = *(const bf16x8*)&sX[fr][k0 + fg * 8];
    bf16x8 af1 = *(const bf16x8*)&sX[16 + fr][k0 + fg * 8];
    #pragma unroll
    for (int n = 0; n < 8; ++n) {
      const __bf16* bp = wf1t + (long)(w * 128 + n * 16 + fr) * HH + k0 + fg * 8;
      bf16x8 bfr = *(const bf16x8*)bp;
      a1[0][n] = mfma16(af0, bfr, a1[0][n]);
      a1[1][n] = mfma16(af1, bfr, a1[1][n]);
    }
  }
  #pragma unroll
  for (int n = 0; n < 8; ++n) {
    float bv = bf1[w * 128 + n * 16 + fr];
    #pragma unroll
    for (int m = 0; m < 2; ++m)
      #pragma unroll
      for (int j = 0; j < 4; ++j)
        sH1[m * 16 + fg * 4 + j][w * 128 + n * 16 + fr] = (__bf16)gelu_f(a1[m][n][j] + bv);
  }
  __syncthreads();

  // GEMM2: h1(32x512) @ wf2(512x128); wave w owns cols [w*32, w*32+32)
  f32x4 a2[2][2];
  #pragma unroll
  for (int m = 0; m < 2; ++m)
    #pragma unroll
    for (int n = 0; n < 2; ++n) a2[m][n] = (f32x4){0.f, 0.f, 0.f, 0.f};
  for (int kc = 0; kc < 16; ++kc) {
    int k0 = kc * 32;
    bf16x8 af0 = *(const bf16x8*)&sH1[fr][k0 + fg * 8];
    bf16x8 af1 = *(const bf16x8*)&sH1[16 + fr][k0 + fg * 8];
    #pragma unroll
    for (int n = 0; n < 2; ++n) {
      const __bf16* bp = wf2t + (long)(w * 32 + n * 16 + fr) * 512 + k0 + fg * 8;
      bf16x8 bfr = *(const bf16x8*)bp;
      a2[0][n] = mfma16(af0, bfr, a2[0][n]);
      a2[1][n] = mfma16(af1, bfr, a2[1][n]);
    }
  }
  #pragma unroll
  for (int n = 0; n < 2; ++n) {
    float bv = bf2[w * 32 + n * 16 + fr];
    #pragma unroll
    for (int m = 0; m < 2; ++m)
      #pragma unroll
      for (int j = 0; j < 4; ++j)
        sOut[m * 16 + fg * 4 + j][w * 32 + n * 16 + fr] = a2[m][n][j] + bv;
  }
  __syncthreads();

  // LN2 + mask_V + store
  {
    int r = tid >> 3, c0 = (tid & 7) * 16;
    long p = row0 + r;
    const float* xp = xin + p * HH + c0;
    float x[16];
    #pragma unroll
    for (int i = 0; i < 16; ++i) x[i] = xp[i] + sOut[r][c0 + i];
    float s = 0.f;
    #pragma unroll
    for (int i = 0; i < 16; ++i) s += x[i];
    s += __shfl_xor(s, 1); s += __shfl_xor(s, 2); s += __shfl_xor(s, 4);
    float mean = s * (1.f / 128.f);
    float q = 0.f;
    #pragma unroll
    for (int i = 0; i < 16; ++i) { float e = x[i] - mean; q += e * e; }
    q += __shfl_xor(q, 1); q += __shfl_xor(q, 2); q += __shfl_xor(q, 4);
    float rs = rsqrtf(q * (1.f / 128.f) + 1e-5f);
    float mv = maskV[p];
    float* op = out + p * HH + c0;
    #pragma unroll
    for (int i = 0; i < 16; ++i)
      op[i] = ((x[i] - mean) * rs * g2[c0 + i] + bn2[c0 + i]) * mv;
  }
}

extern "C" void kernel_launch(void* const* d_in, const int* in_sizes, int n_in,
                              void* d_out, int out_size, void* d_ws, size_t ws_size,
                              hipStream_t stream) {
  const float* hV    = (const float*)d_in[0];
  const float* hE    = (const float*)d_in[1];
  const float* maskV = (const float*)d_in[2];
  const float* maskE = (const float*)d_in[3];
  const float* w1    = (const float*)d_in[4];
  const float* b1    = (const float*)d_in[5];
  const float* w2    = (const float*)d_in[6];
  const float* b2    = (const float*)d_in[7];
  const float* w3    = (const float*)d_in[8];
  const float* b3    = (const float*)d_in[9];
  const float* g1    = (const float*)d_in[10];
  const float* bn1   = (const float*)d_in[11];
  const float* g2    = (const float*)d_in[12];
  const float* bn2   = (const float*)d_in[13];
  const float* wf1   = (const float*)d_in[14];
  const float* bf1   = (const float*)d_in[15];
  const float* wf2   = (const float*)d_in[16];
  const float* bf2   = (const float*)d_in[17];
  float* out = (float*)d_out;

  __bf16* wsb = (__bf16*)d_ws;                           // 212992 bf16 elems
  float* V1   = (float*)((char*)d_ws + 425984);          // [8192][128] f32
  float* hbuf = (float*)((char*)d_ws + 4620288);         // [8192][128] f32
  // requires ws_size >= 8,814,592 bytes

  prep_kernel<<<832, 256, 0, stream>>>(w1, w2, w3, wf1, wf2, wsb);
  v1_kernel<<<512, 128, 0, stream>>>(hV, w1, b1, V1);
  msg_kernel<<<2048, 256, 0, stream>>>(hE, hV, maskE,
                                       wsb, wsb + 49152, wsb + 65536, V1,
                                       b2, b3, g1, bn1, hbuf);
  ffn_kernel<<<256, 256, 0, stream>>>(hbuf, wsb + 81920, bf1, wsb + 147456, bf2,
                                      g2, bn2, maskV, out);
}

// Round 6
// 211.946 us; speedup vs baseline: 1.1539x; 1.1539x over previous
//
#include <hip/hip_runtime.h>
#include <hip/hip_bf16.h>

// DecLayer: h_V(4,2048,128) h_E(4,2048,48,384) f32 -> out(4,2048,128) f32
// ws layout (bytes): [0, 425984) bf16 weights (w1f,w2f,w3f fragment-order; wf1t,wf2t row-order)
//                    [425984, 4620288) V1 f32 [8192][128]
//                    [4620288, 8814592) h (post-LN1) f32 [8192][128]

typedef __bf16 bf16x8 __attribute__((ext_vector_type(8)));
typedef __bf16 bf16x4 __attribute__((ext_vector_type(4)));
typedef float f32x4 __attribute__((ext_vector_type(4)));

#define HH 128
#define EE 384
#define KK 48

__device__ __forceinline__ float gelu_f(float x) {
  // tanh-approx gelu = x * sigmoid(2*(0.79788456 x + 0.03567741 x^3))
  float x2 = x * x;
  float u = x * (-1.5957691216f - 0.0713548163f * x2);
  float e = __expf(u);
  return __fdividef(x, 1.0f + e);
}

__device__ __forceinline__ bf16x8 cvt8v(f32x4 a, f32x4 b) {
  bf16x8 r;
  #pragma unroll
  for (int i = 0; i < 4; ++i) { r[i] = (__bf16)a[i]; r[i + 4] = (__bf16)b[i]; }
  return r;
}

__device__ __forceinline__ f32x4 mfma16(bf16x8 a, bf16x8 b, f32x4 c) {
  return __builtin_amdgcn_mfma_f32_16x16x32_bf16(a, b, c, 0, 0, 0);
}

__device__ __forceinline__ void gload16(const void* g, void* l) {
  __builtin_amdgcn_global_load_lds(
      (const __attribute__((address_space(1))) void*)g,
      (__attribute__((address_space(3))) void*)l, 16, 0, 0);
}

// ---------------- weight prep ----------------
// w1f/w2f/w3f in MFMA-fragment order: elem(kc,n,lane,t) = W^T[n*16+(lane&15)][kc*32+(lane>>4)*8+t]
// so a wave's B-load for (kc,n) is ONE contiguous 1KB fetch at ((kc*8+n)*64+lane)*8.
__global__ void prep_kernel(const float* __restrict__ w1, const float* __restrict__ w2,
                            const float* __restrict__ w3, const float* __restrict__ wf1,
                            const float* __restrict__ wf2, __bf16* __restrict__ out) {
  int idx = blockIdx.x * 256 + threadIdx.x;
  if (idx < 49152) {                       // w1f (edge part of w1: rows 128..511)
    int t = idx & 7, lane = (idx >> 3) & 63, n = (idx >> 9) & 7, kc = idx >> 12;
    int e = kc * 32 + (lane >> 4) * 8 + t, h = n * 16 + (lane & 15);
    out[idx] = (__bf16)w1[(128 + e) * 128 + h];
  } else if (idx < 65536) {                // w2f
    int u = idx - 49152;
    int t = u & 7, lane = (u >> 3) & 63, n = (u >> 9) & 7, kc = u >> 12;
    int e = kc * 32 + (lane >> 4) * 8 + t, h = n * 16 + (lane & 15);
    out[idx] = (__bf16)w2[e * 128 + h];
  } else if (idx < 81920) {                // w3f
    int u = idx - 65536;
    int t = u & 7, lane = (u >> 3) & 63, n = (u >> 9) & 7, kc = u >> 12;
    int e = kc * 32 + (lane >> 4) * 8 + t, h = n * 16 + (lane & 15);
    out[idx] = (__bf16)w3[e * 128 + h];
  } else if (idx < 147456) {               // wf1t[512][128]: wf1t[f][h] = wf1[h][f]
    int t = idx - 81920; int f = t >> 7, h = t & 127;
    out[idx] = (__bf16)wf1[h * 512 + f];
  } else if (idx < 212992) {               // wf2t[128][512]: wf2t[h][f] = wf2[f][h]
    int t = idx - 147456; int h = t >> 9, f = t & 511;
    out[idx] = (__bf16)wf2[f * 128 + h];
  }
}

// ---------------- V1[p][h] = b1[h] + sum_i h_V[p][i] * w1[i][h]  (i<128) ----------------
__global__ __launch_bounds__(128) void v1_kernel(const float* __restrict__ hV,
                                                 const float* __restrict__ w1,
                                                 const float* __restrict__ b1,
                                                 float* __restrict__ V1) {
  __shared__ __align__(16) float sV[16][128];
  const int tid = threadIdx.x;
  const long p0 = (long)blockIdx.x * 16;
  for (int i = 0; i < 16; ++i) sV[i][tid] = hV[(p0 + i) * HH + tid];
  __syncthreads();
  float acc[16];
  float bb = b1[tid];
  #pragma unroll
  for (int p = 0; p < 16; ++p) acc[p] = bb;
  for (int k = 0; k < 128; k += 4) {
    float wa = w1[(k + 0) * HH + tid];
    float wb = w1[(k + 1) * HH + tid];
    float wc = w1[(k + 2) * HH + tid];
    float wd = w1[(k + 3) * HH + tid];
    #pragma unroll
    for (int p = 0; p < 16; ++p) {
      float4 h4 = *(const float4*)&sV[p][k];
      acc[p] = fmaf(h4.x, wa, fmaf(h4.y, wb, fmaf(h4.z, wc, fmaf(h4.w, wd, acc[p]))));
    }
  }
  #pragma unroll
  for (int p = 0; p < 16; ++p) V1[(p0 + p) * HH + tid] = acc[p];
}

// ---------------- fused message kernel ----------------
// 4 waves/block, wave w owns position blockIdx.x*4+w end-to-end. No barriers.
// GEMM1: depth-2 counted-vmcnt pipeline over 3 rotating wave-private 6KB LDS A-buffers;
// B(k) in parity register set k%2 (no copies). Steady wait vmcnt(14) = leave A(k+1),B(k+1).
// After GEMM1, staging bufs 0-1 (12KB) are reused as the h1/h2 buffer (48 x 256B rows).
// Swapped MFMA: lane (fr,fg) holds acc[m][n][j] = h_msg[msg=m*16+fr][h=n*16+fg*4+j].
__global__ __launch_bounds__(256, 2) void msg_kernel(
    const float* __restrict__ hE, const float* __restrict__ hV,
    const float* __restrict__ maskE,
    const __bf16* __restrict__ w1f, const __bf16* __restrict__ w2f,
    const __bf16* __restrict__ w3f, const float* __restrict__ V1,
    const float* __restrict__ b2, const float* __restrict__ b3,
    const float* __restrict__ g1, const float* __restrict__ bn1,
    float* __restrict__ outH) {
  __shared__ __align__(16) float sStage[4][4608];   // 18KB/wave: 3 x 6KB A-bufs; bufs0-1 reused as h

  const int tid = threadIdx.x;
  const int lane = tid & 63;
  const int w = tid >> 6;
  const long p = (long)blockIdx.x * 4 + w;
  const int fr = lane & 15;
  const int fg = lane >> 4;
  char* stDst = (char*)&sStage[w][0];
  const int swz = (fr & 7) << 4;

  const int r_l = lane >> 3;                        // 0..7
  const int cswz = ((lane & 7) ^ r_l) * 16;         // pre-swizzled source col-bytes
  const char* gA = (const char*)(hE + p * KK * (long)EE) + r_l * (EE * 4) + cswz;

  const __bf16* b1p = w1f + lane * 8;
  const __bf16* b2p = w2f + lane * 8;
  const __bf16* b3p = w3f + lane * 8;

  f32x4 acc[3][8];
  #pragma unroll
  for (int m = 0; m < 3; ++m)
    #pragma unroll
    for (int n = 0; n < 8; ++n) acc[m][n] = (f32x4){0.f, 0.f, 0.f, 0.f};

  bf16x8 BsA[8], BsB[8];   // parity B-register sets

#define STAGEA(KC, BUFI) { \
    _Pragma("unroll") for (int q_ = 0; q_ < 6; ++q_) \
      gload16(gA + (KC) * 128 + q_ * (8 * EE * 4), stDst + (BUFI) * 6144 + q_ * 1024); }
#define LOADB(BUF, BP, KC) { \
    _Pragma("unroll") for (int n_ = 0; n_ < 8; ++n_) \
      BUF[n_] = *(const bf16x8*)((BP) + ((KC) * 8 + n_) * 512); }
#define WAITV(N) asm volatile("s_waitcnt vmcnt(" #N ")" ::: "memory")

// One GEMM1 iteration: wait A(k),B(k) landed (counted) -> ds_read A(k) -> stage A(k+2)
// -> MFMA with B(k) -> load B(k+2) into the same parity set (after MFMAs via WAR).
#define GITER(WAITN, BUFI, BUSE, DOSTAGE, STKC, STBUF, DOB, BLP, BLKC) { \
    WAITV(WAITN); \
    const char* rb_ = stDst + (BUFI) * 6144; \
    f32x4 x0_ = *(const f32x4*)(rb_ + fr * 128 + ((fg * 32) ^ swz)); \
    f32x4 x1_ = *(const f32x4*)(rb_ + fr * 128 + ((fg * 32 + 16) ^ swz)); \
    f32x4 x2_ = *(const f32x4*)(rb_ + (16 + fr) * 128 + ((fg * 32) ^ swz)); \
    f32x4 x3_ = *(const f32x4*)(rb_ + (16 + fr) * 128 + ((fg * 32 + 16) ^ swz)); \
    f32x4 x4_ = *(const f32x4*)(rb_ + (32 + fr) * 128 + ((fg * 32) ^ swz)); \
    f32x4 x5_ = *(const f32x4*)(rb_ + (32 + fr) * 128 + ((fg * 32 + 16) ^ swz)); \
    if (DOSTAGE) STAGEA(STKC, STBUF); \
    bf16x8 af0 = cvt8v(x0_, x1_); \
    bf16x8 af1 = cvt8v(x2_, x3_); \
    bf16x8 af2 = cvt8v(x4_, x5_); \
    _Pragma("unroll") for (int n_ = 0; n_ < 8; ++n_) { \
      acc[0][n_] = mfma16(BUSE[n_], af0, acc[0][n_]); \
      acc[1][n_] = mfma16(BUSE[n_], af1, acc[1][n_]); \
      acc[2][n_] = mfma16(BUSE[n_], af2, acc[2][n_]); } \
    if (DOB) LOADB(BUSE, BLP, BLKC); }

#define STEPL(BUSE, KC, DOB, BLP, BLKC) { \
    const int cb_ = (((KC) * 64 + fg * 16) ^ swz); \
    bf16x8 af0 = *(const bf16x8*)(stDst + fr * 256 + cb_); \
    bf16x8 af1 = *(const bf16x8*)(stDst + (16 + fr) * 256 + cb_); \
    bf16x8 af2 = *(const bf16x8*)(stDst + (32 + fr) * 256 + cb_); \
    _Pragma("unroll") for (int n_ = 0; n_ < 8; ++n_) { \
      acc[0][n_] = mfma16(BUSE[n_], af0, acc[0][n_]); \
      acc[1][n_] = mfma16(BUSE[n_], af1, acc[1][n_]); \
      acc[2][n_] = mfma16(BUSE[n_], af2, acc[2][n_]); } \
    if (DOB) LOADB(BUSE, BLP, BLKC); }

#define EPI(BIASQ) { \
    _Pragma("unroll") for (int m_ = 0; m_ < 3; ++m_) { \
      const int rb_ = (m_ * 16 + fr) * 256; \
      _Pragma("unroll") for (int n_ = 0; n_ < 8; ++n_) { \
        bf16x4 t_; \
        _Pragma("unroll") for (int j_ = 0; j_ < 4; ++j_) \
          t_[j_] = (__bf16)gelu_f(acc[m_][n_][j_] + BIASQ[n_][j_]); \
        *(bf16x4*)(stDst + rb_ + ((n_ * 32 + fg * 8) ^ swz)) = t_; \
        acc[m_][n_] = (f32x4){0.f, 0.f, 0.f, 0.f}; } } }

  // ---- prologue: queue = [A0(6) B0(8) A1(6) B1(8)] = 28 outstanding ----
  STAGEA(0, 0);
  LOADB(BsA, b1p, 0);
  STAGEA(1, 1);
  LOADB(BsB, b1p, 1);

  // ---- GEMM1: 12 iterations; steady-state wait vmcnt(14) leaves A(k+1),B(k+1) in flight ----
  GITER(14, 0, BsA, 1, 2, 2, 1, b1p, 2);    // k=0
  GITER(14, 1, BsB, 1, 3, 0, 1, b1p, 3);    // k=1
  GITER(14, 2, BsA, 1, 4, 1, 1, b1p, 4);    // k=2
  GITER(14, 0, BsB, 1, 5, 2, 1, b1p, 5);    // k=3
  GITER(14, 1, BsA, 1, 6, 0, 1, b1p, 6);    // k=4
  GITER(14, 2, BsB, 1, 7, 1, 1, b1p, 7);    // k=5
  GITER(14, 0, BsA, 1, 8, 2, 1, b1p, 8);    // k=6
  GITER(14, 1, BsB, 1, 9, 0, 1, b1p, 9);    // k=7
  GITER(14, 2, BsA, 1, 10, 1, 1, b1p, 10);  // k=8
  GITER(14, 0, BsB, 1, 11, 2, 1, b1p, 11);  // k=9

  // early V1 row load (8 vmem ops) so EPI1's wait leaves GEMM2 B-prefetch in flight
  f32x4 vq[8];
  #pragma unroll
  for (int n = 0; n < 8; ++n) vq[n] = *(const f32x4*)(V1 + p * HH + n * 16 + fg * 4);

  GITER(22, 1, BsA, 0, 0, 0, 1, b2p, 0);    // k=10; load GEMM2 B0 -> setA
  GITER(16, 2, BsB, 0, 0, 0, 1, b2p, 1);    // k=11; load GEMM2 B1 -> setB

  // epilogue 1: + V1 (has b1), gelu -> h1 in reused staging LDS (wave-local)
  EPI(vq);

  // ---- GEMM2: h1(48x128) @ w2 ----
  { WAITV(8);  STEPL(BsA, 0, 1, b2p, 2); }
  { WAITV(8);  STEPL(BsB, 1, 1, b2p, 3); }
  { WAITV(8);  STEPL(BsA, 2, 1, b3p, 0); }
  { WAITV(8);  STEPL(BsB, 3, 1, b3p, 1); }
  {
    f32x4 bq[8];
    #pragma unroll
    for (int n = 0; n < 8; ++n) bq[n] = *(const f32x4*)(b2 + n * 16 + fg * 4);
    EPI(bq);
  }

  // ---- GEMM3: h2(48x128) @ w3 ----
  { STEPL(BsA, 0, 1, b3p, 2); }
  { STEPL(BsB, 1, 1, b3p, 3); }
  { WAITV(8);  STEPL(BsA, 2, 0, b3p, 0); }
  { WAITV(0);  STEPL(BsB, 3, 0, b3p, 0); }

  // ---- masked K-reduction, fully in-register ----
  const float mk0 = maskE[p * KK + fr];
  const float mk1 = maskE[p * KK + 16 + fr];
  const float mk2 = maskE[p * KK + 32 + fr];
  f32x4 red[8];
  {
    #pragma unroll
    for (int n = 0; n < 8; ++n) {
      f32x4 bq = *(const f32x4*)(b3 + n * 16 + fg * 4);
      red[n] = mk0 * (acc[0][n] + bq) + mk1 * (acc[1][n] + bq) + mk2 * (acc[2][n] + bq);
    }
    #pragma unroll
    for (int off = 1; off <= 8; off <<= 1)
      #pragma unroll
      for (int n = 0; n < 8; ++n)
        #pragma unroll
        for (int j = 0; j < 4; ++j)
          red[n][j] += __shfl_xor(red[n][j], off);
  }

  // ---- LN1: x = hV + dh/30, normalize over 128 ----
  {
    f32x4 xq[8];
    #pragma unroll
    for (int n = 0; n < 8; ++n)
      xq[n] = *(const f32x4*)(hV + p * HH + n * 16 + fg * 4) + red[n] * (1.f / 30.f);
    float s = 0.f;
    #pragma unroll
    for (int n = 0; n < 8; ++n)
      #pragma unroll
      for (int j = 0; j < 4; ++j) s += xq[n][j];
    s += __shfl_xor(s, 16); s += __shfl_xor(s, 32);
    float mean = s * (1.f / 128.f);
    float qv = 0.f;
    #pragma unroll
    for (int n = 0; n < 8; ++n)
      #pragma unroll
      for (int j = 0; j < 4; ++j) { float e = xq[n][j] - mean; qv += e * e; }
    qv += __shfl_xor(qv, 16); qv += __shfl_xor(qv, 32);
    float rs = rsqrtf(qv * (1.f / 128.f) + 1e-5f);
    if (fr == 0) {
      #pragma unroll
      for (int n = 0; n < 8; ++n) {
        f32x4 gq = *(const f32x4*)(g1 + n * 16 + fg * 4);
        f32x4 bq = *(const f32x4*)(bn1 + n * 16 + fg * 4);
        f32x4 o;
        #pragma unroll
        for (int j = 0; j < 4; ++j) o[j] = (xq[n][j] - mean) * rs * gq[j] + bq[j];
        *(f32x4*)(outH + p * HH + n * 16 + fg * 4) = o;
      }
    }
  }
#undef STAGEA
#undef LOADB
#undef WAITV
#undef GITER
#undef STEPL
#undef EPI
}

// ---------------- FFN + LN2 + mask ----------------
__global__ __launch_bounds__(256, 2) void ffn_kernel(
    const float* __restrict__ xin, const __bf16* __restrict__ wf1t,
    const float* __restrict__ bf1, const __bf16* __restrict__ wf2t,
    const float* __restrict__ bf2, const float* __restrict__ g2,
    const float* __restrict__ bn2, const float* __restrict__ maskV,
    float* __restrict__ out) {
  __shared__ __align__(16) __bf16 sX[32][136];
  __shared__ __align__(16) __bf16 sH1[32][520];
  __shared__ __align__(16) float sOut[32][132];
  const int tid = threadIdx.x, lane = tid & 63, w = tid >> 6;
  const long row0 = (long)blockIdx.x * 32;
  const int fr = lane & 15, fg = lane >> 4;

  {  // stage X -> bf16
    int r = tid >> 3, c = (tid & 7) * 16;
    const float* src = xin + (row0 + r) * HH + c;
    f32x4 v0 = *(const f32x4*)src, v1 = *(const f32x4*)(src + 4);
    f32x4 v2 = *(const f32x4*)(src + 8), v3 = *(const f32x4*)(src + 12);
    *(bf16x8*)&sX[r][c] = cvt8v(v0, v1);
    *(bf16x8*)&sX[r][c + 8] = cvt8v(v2, v3);
  }
  __syncthreads();

  // GEMM1: x(32x128) @ wf1(128x512); wave w owns cols [w*128, w*128+128)
  f32x4 a1[2][8];
  #pragma unroll
  for (int m = 0; m < 2; ++m)
    #pragma unroll
    for (int n = 0; n < 8; ++n) a1[m][n] = (f32x4){0.f, 0.f, 0.f, 0.f};
  for (int kc = 0; kc < 4; ++kc) {
    int k0 = kc * 32;
    bf16x8 af0 = *(const bf16x8*)&sX[fr][k0 + fg * 8];
    bf16x8 af1 = *(const bf16x8*)&sX[16 + fr][k0 + fg * 8];
    #pragma unroll
    for (int n = 0; n < 8; ++n) {
      const __bf16* bp = wf1t + (long)(w * 128 + n * 16 + fr) * HH + k0 + fg * 8;
      bf16x8 bfr = *(const bf16x8*)bp;
      a1[0][n] = mfma16(af0, bfr, a1[0][n]);
      a1[1][n] = mfma16(af1, bfr, a1[1][n]);
    }
  }
  #pragma unroll
  for (int n = 0; n < 8; ++n) {
    float bv = bf1[w * 128 + n * 16 + fr];
    #pragma unroll
    for (int m = 0; m < 2; ++m)
      #pragma unroll
      for (int j = 0; j < 4; ++j)
        sH1[m * 16 + fg * 4 + j][w * 128 + n * 16 + fr] = (__bf16)gelu_f(a1[m][n][j] + bv);
  }
  __syncthreads();

  // GEMM2: h1(32x512) @ wf2(512x128); wave w owns cols [w*32, w*32+32)
  f32x4 a2[2][2];
  #pragma unroll
  for (int m = 0; m < 2; ++m)
    #pragma unroll
    for (int n = 0; n < 2; ++n) a2[m][n] = (f32x4){0.f, 0.f, 0.f, 0.f};
  for (int kc = 0; kc < 16; ++kc) {
    int k0 = kc * 32;
    bf16x8 af0 = *(const bf16x8*)&sH1[fr][k0 + fg * 8];
    bf16x8 af1 = *(const bf16x8*)&sH1[16 + fr][k0 + fg * 8];
    #pragma unroll
    for (int n = 0; n < 2; ++n) {
      const __bf16* bp = wf2t + (long)(w * 32 + n * 16 + fr) * 512 + k0 + fg * 8;
      bf16x8 bfr = *(const bf16x8*)bp;
      a2[0][n] = mfma16(af0, bfr, a2[0][n]);
      a2[1][n] = mfma16(af1, bfr, a2[1][n]);
    }
  }
  #pragma unroll
  for (int n = 0; n < 2; ++n) {
    float bv = bf2[w * 32 + n * 16 + fr];
    #pragma unroll
    for (int m = 0; m < 2; ++m)
      #pragma unroll
      for (int j = 0; j < 4; ++j)
        sOut[m * 16 + fg * 4 + j][w * 32 + n * 16 + fr] = a2[m][n][j] + bv;
  }
  __syncthreads();

  // LN2 + mask_V + store
  {
    int r = tid >> 3, c0 = (tid & 7) * 16;
    long p = row0 + r;
    const float* xp = xin + p * HH + c0;
    float x[16];
    #pragma unroll
    for (int i = 0; i < 16; ++i) x[i] = xp[i] + sOut[r][c0 + i];
    float s = 0.f;
    #pragma unroll
    for (int i = 0; i < 16; ++i) s += x[i];
    s += __shfl_xor(s, 1); s += __shfl_xor(s, 2); s += __shfl_xor(s, 4);
    float mean = s * (1.f / 128.f);
    float q = 0.f;
    #pragma unroll
    for (int i = 0; i < 16; ++i) { float e = x[i] - mean; q += e * e; }
    q += __shfl_xor(q, 1); q += __shfl_xor(q, 2); q += __shfl_xor(q, 4);
    float rs = rsqrtf(q * (1.f / 128.f) + 1e-5f);
    float mv = maskV[p];
    float* op = out + p * HH + c0;
    #pragma unroll
    for (int i = 0; i < 16; ++i)
      op[i] = ((x[i] - mean) * rs * g2[c0 + i] + bn2[c0 + i]) * mv;
  }
}

extern "C" void kernel_launch(void* const* d_in, const int* in_sizes, int n_in,
                              void* d_out, int out_size, void* d_ws, size_t ws_size,
                              hipStream_t stream) {
  const float* hV    = (const float*)d_in[0];
  const float* hE    = (const float*)d_in[1];
  const float* maskV = (const float*)d_in[2];
  const float* maskE = (const float*)d_in[3];
  const float* w1    = (const float*)d_in[4];
  const float* b1    = (const float*)d_in[5];
  const float* w2    = (const float*)d_in[6];
  const float* b2    = (const float*)d_in[7];
  const float* w3    = (const float*)d_in[8];
  const float* b3    = (const float*)d_in[9];
  const float* g1    = (const float*)d_in[10];
  const float* bn1   = (const float*)d_in[11];
  const float* g2    = (const float*)d_in[12];
  const float* bn2   = (const float*)d_in[13];
  const float* wf1   = (const float*)d_in[14];
  const float* bf1   = (const float*)d_in[15];
  const float* wf2   = (const float*)d_in[16];
  const float* bf2   = (const float*)d_in[17];
  float* out = (float*)d_out;

  __bf16* wsb = (__bf16*)d_ws;                           // 212992 bf16 elems
  float* V1   = (float*)((char*)d_ws + 425984);          // [8192][128] f32
  float* hbuf = (float*)((char*)d_ws + 4620288);         // [8192][128] f32
  // requires ws_size >= 8,814,592 bytes

  prep_kernel<<<832, 256, 0, stream>>>(w1, w2, w3, wf1, wf2, wsb);
  v1_kernel<<<512, 128, 0, stream>>>(hV, w1, b1, V1);
  msg_kernel<<<2048, 256, 0, stream>>>(hE, hV, maskE,
                                       wsb, wsb + 49152, wsb + 65536, V1,
                                       b2, b3, g1, bn1, hbuf);
  ffn_kernel<<<256, 256, 0, stream>>>(hbuf, wsb + 81920, bf1, wsb + 147456, bf2,
                                      g2, bn2, maskV, out);
}